// Round 4
// baseline (4423.666 us; speedup 1.0000x reference)
//
#include <hip/hip_runtime.h>

// GCN3: 3x (COO spmm -> Linear(64) -> ReLU), segment-mean pool, softmax head.
// relu(spmm(X)@W + b) == relu(spmm(X@W) + b): dense transform first.
// Edges are binned into 512-row buckets (LDS-staged for write-combining),
// then spmm runs PUSH-style per bucket with a 512x64 fp32 LDS accumulator.
// No per-row CSR, no global scatter, no global f32 atomics in the hot path.

#define BSHIFT 9
#define BROWS  (1 << BSHIFT)   // 512 rows per bucket
#define MAXK   256             // supports N <= 131072
#define CHUNK  4096            // edges per binpass block

__device__ inline unsigned short f2bf(float f) {  // RNE bf16
    unsigned u = __float_as_uint(f);
    u += 0x7fffu + ((u >> 16) & 1u);
    return (unsigned short)(u >> 16);
}
__device__ inline float bf2f(unsigned short h) {
    return __uint_as_float((unsigned)h << 16);
}

// Per-block LDS histogram of bucket ids -> global bucket counts.
__global__ __launch_bounds__(256) void bhist_k(const int* __restrict__ rows,
                                               int* __restrict__ bhist, int E) {
    __shared__ int h[MAXK];
    int tx = threadIdx.x;
    h[tx] = 0;
    __syncthreads();
    int e0 = blockIdx.x * CHUNK, ee = min(e0 + CHUNK, E);
    for (int e = e0 + tx; e < ee; e += 256) atomicAdd(&h[rows[e] >> BSHIFT], 1);
    __syncthreads();
    if (h[tx]) atomicAdd(&bhist[tx], h[tx]);
}

// Exclusive scan of bucket counts (single block); init padded cursors.
__global__ __launch_bounds__(MAXK) void bscan_k(const int* __restrict__ bhist,
                                                int* __restrict__ bstart,
                                                int* __restrict__ bcur, int K, int E) {
    __shared__ int s[MAXK];
    int tx = threadIdx.x;
    int v = (tx < K) ? bhist[tx] : 0;
    s[tx] = v;
    __syncthreads();
    for (int off = 1; off < MAXK; off <<= 1) {
        int t = (tx >= off) ? s[tx - off] : 0;
        __syncthreads();
        s[tx] += t;
        __syncthreads();
    }
    if (tx < K) {
        bstart[tx] = s[tx] - v;
        bcur[tx * 16] = s[tx] - v;  // 1 cursor per 64B line
    }
    if (tx == K - 1) bstart[K] = E;
}

// Bin edges by bucket, staged in LDS so global writes are contiguous
// single-CU bursts (fixes the 6.4x cross-XCD write amplification of r3).
// Record: x = (col<<9)|(row&511), y = val bits.
__global__ __launch_bounds__(256) void binpass_k(
    const int* __restrict__ rows, const int* __restrict__ cols,
    const float* __restrict__ vals, int* __restrict__ bcur,
    int2* __restrict__ pk, int E) {
    __shared__ int h[MAXK], base[MAXK], gbase[MAXK], lcnt[MAXK];
    __shared__ int2 st[CHUNK];
    int tx = threadIdx.x;
    h[tx] = 0;
    __syncthreads();
    int e0 = blockIdx.x * CHUNK, ee = min(e0 + CHUNK, E);
    for (int e = e0 + tx; e < ee; e += 256) atomicAdd(&h[rows[e] >> BSHIFT], 1);
    __syncthreads();
    int v = h[tx];
    lcnt[tx] = v;  // reuse as scan buffer
    __syncthreads();
    for (int off = 1; off < MAXK; off <<= 1) {
        int t = (tx >= off) ? lcnt[tx - off] : 0;
        __syncthreads();
        lcnt[tx] += t;
        __syncthreads();
    }
    base[tx] = lcnt[tx] - v;
    if (v) gbase[tx] = atomicAdd(&bcur[tx * 16], v);
    lcnt[tx] = 0;
    __syncthreads();
    for (int e = e0 + tx; e < ee; e += 256) {
        int r = rows[e];
        int b = r >> BSHIFT;
        int p = base[b] + atomicAdd(&lcnt[b], 1);
        st[p] = make_int2((cols[e] << BSHIFT) | (r & (BROWS - 1)),
                          __float_as_int(vals[e]));
    }
    __syncthreads();
    // flush contiguous per-bucket runs, wave-parallel
    int lane = tx & 63, wid = tx >> 6;
    for (int b = wid; b < MAXK; b += 4) {
        int cnt = h[b];
        if (!cnt) continue;
        int lb = base[b], gb = gbase[b];
        for (int i = lane; i < cnt; i += 64) pk[gb + i] = st[lb + i];
    }
}

// Z0 = bf16(X @ W1), X:[n,5]. Wave per row, lane = out dim.
__global__ __launch_bounds__(256) void dense5_k(
    const float* __restrict__ X, const float* __restrict__ W,
    unsigned short* __restrict__ Zb, int n) {
    int lane = threadIdx.x & 63;
    int row = (blockIdx.x * blockDim.x + threadIdx.x) >> 6;
    if (row >= n) return;
    float w0 = W[lane], w1 = W[64 + lane], w2 = W[128 + lane],
          w3 = W[192 + lane], w4 = W[256 + lane];
    float xv = (lane < 5) ? X[(size_t)row * 5 + lane] : 0.f;
    float y = __shfl(xv, 0, 64) * w0;
    y = fmaf(__shfl(xv, 1, 64), w1, y);
    y = fmaf(__shfl(xv, 2, 64), w2, y);
    y = fmaf(__shfl(xv, 3, 64), w3, y);
    y = fmaf(__shfl(xv, 4, 64), w4, y);
    Zb[(size_t)row * 64 + lane] = f2bf(y);
}

// Zb = bf16(X @ W), X:[n,64] fp32, W in LDS. Wave per row, lane = out dim.
__global__ __launch_bounds__(256) void dense64_k(
    const float* __restrict__ X, const float* __restrict__ W,
    unsigned short* __restrict__ Zb, int n) {
    __shared__ float Ws[64 * 64];
    int tx = threadIdx.x, lane = tx & 63;
    for (int i = tx; i < 4096; i += 256) Ws[i] = W[i];
    __syncthreads();
    int row = (blockIdx.x * blockDim.x + tx) >> 6;
    if (row >= n) return;
    const float4* xr = (const float4*)(X + (size_t)row * 64);
    float y = 0.f;
#pragma unroll
    for (int k4 = 0; k4 < 16; ++k4) {
        float4 xv = xr[k4];  // wave-uniform broadcast
        int k = k4 * 4;
        y = fmaf(xv.x, Ws[(k + 0) * 64 + lane], y);
        y = fmaf(xv.y, Ws[(k + 1) * 64 + lane], y);
        y = fmaf(xv.z, Ws[(k + 2) * 64 + lane], y);
        y = fmaf(xv.w, Ws[(k + 3) * 64 + lane], y);
    }
    Zb[(size_t)row * 64 + lane] = f2bf(y);
}

// Push spmm: one block per 512-row bucket, fp32 accumulator in LDS (128KB).
// Each wave: 4 independent edge gathers in flight; ds_add_f32 accumulate
// (lane->bank is 2-way aliased = free). Epilogue: bias + relu + store.
__global__ __launch_bounds__(512) void spmm_push_k(
    const int* __restrict__ bstart, const int2* __restrict__ pk,
    const unsigned short* __restrict__ Zb, const float* __restrict__ bias,
    float* __restrict__ xout, int n) {
    __shared__ float acc[BROWS * 64];
    int tx = threadIdx.x, lane = tx & 63, wid = tx >> 6;
    for (int i = tx; i < BROWS * 64; i += 512) acc[i] = 0.f;
    __syncthreads();
    int b = blockIdx.x;
    int row0 = b << BSHIFT;
    int s = bstart[b], e = bstart[b + 1];
    for (int j0 = s + wid * 4; j0 < e; j0 += 32) {
        if (j0 + 4 <= e) {
            int2 p0 = pk[j0], p1 = pk[j0 + 1], p2 = pk[j0 + 2], p3 = pk[j0 + 3];
            float z0 = bf2f(Zb[(size_t)(p0.x >> BSHIFT) * 64 + lane]);
            float z1 = bf2f(Zb[(size_t)(p1.x >> BSHIFT) * 64 + lane]);
            float z2 = bf2f(Zb[(size_t)(p2.x >> BSHIFT) * 64 + lane]);
            float z3 = bf2f(Zb[(size_t)(p3.x >> BSHIFT) * 64 + lane]);
            atomicAdd(&acc[(p0.x & (BROWS - 1)) * 64 + lane], __int_as_float(p0.y) * z0);
            atomicAdd(&acc[(p1.x & (BROWS - 1)) * 64 + lane], __int_as_float(p1.y) * z1);
            atomicAdd(&acc[(p2.x & (BROWS - 1)) * 64 + lane], __int_as_float(p2.y) * z2);
            atomicAdd(&acc[(p3.x & (BROWS - 1)) * 64 + lane], __int_as_float(p3.y) * z3);
        } else {
            for (int j = j0; j < e; ++j) {
                int2 p = pk[j];
                float z = bf2f(Zb[(size_t)(p.x >> BSHIFT) * 64 + lane]);
                atomicAdd(&acc[(p.x & (BROWS - 1)) * 64 + lane], __int_as_float(p.y) * z);
            }
        }
    }
    __syncthreads();
    float bv = bias[lane];
    int nrows = min(BROWS, n - row0);
    for (int r = wid; r < nrows; r += 8)
        xout[(size_t)(row0 + r) * 64 + lane] = fmaxf(acc[r * 64 + lane] + bv, 0.f);
}

// Pool: batch sorted -> run-length accumulate 64 nodes per wave, one
// atomicAdd per segment boundary per lane.
__global__ void pool_k(const float* __restrict__ x1, const float* __restrict__ x2,
                       const float* __restrict__ x3, const int* __restrict__ batch,
                       float* __restrict__ sums, int* __restrict__ cnts, int n) {
    int lane = threadIdx.x & 63;
    int w = (blockIdx.x * blockDim.x + threadIdx.x) >> 6;
    int node0 = w * 64;
    if (node0 >= n) return;
    int cur = batch[node0];
    float acc = 0.f;
    int cnt = 0;
    int end = min(node0 + 64, n);
    for (int nd = node0; nd < end; ++nd) {
        int bg = batch[nd];  // wave-uniform
        if (bg != cur) {
            atomicAdd(&sums[(size_t)cur * 64 + lane], acc);
            if (lane == 0) atomicAdd(&cnts[cur], cnt);
            acc = 0.f;
            cnt = 0;
            cur = bg;
        }
        size_t o = (size_t)nd * 64 + lane;
        acc += x1[o] + x2[o] + x3[o];
        cnt++;
    }
    atomicAdd(&sums[(size_t)cur * 64 + lane], acc);
    if (lane == 0) atomicAdd(&cnts[cur], cnt);
}

// Head: pooled = sums/(3*cnt); out = softmax(pooled @ Wl + bl). Wave per graph.
__global__ void final_k(const float* __restrict__ sums, const int* __restrict__ cnts,
                        const float* __restrict__ Wl, const float* __restrict__ bl,
                        float* __restrict__ out, int G) {
    int lane = threadIdx.x & 63;
    int g = (blockIdx.x * blockDim.x + threadIdx.x) >> 6;
    if (g >= G) return;
    float c = (float)max(cnts[g], 1);
    float s = sums[(size_t)g * 64 + lane] / (3.f * c);
    float y = (lane < 10) ? bl[lane] : -1e30f;
    for (int k = 0; k < 64; ++k) {
        float sk = __shfl(s, k, 64);
        if (lane < 10) y = fmaf(sk, Wl[k * 10 + lane], y);
    }
    float m = y;
#pragma unroll
    for (int off = 8; off; off >>= 1) m = fmaxf(m, __shfl_xor(m, off, 16));
    float ey = (lane < 10) ? __expf(y - m) : 0.f;
    float sm = ey;
#pragma unroll
    for (int off = 8; off; off >>= 1) sm += __shfl_xor(sm, off, 16);
    if (lane < 10) out[(size_t)g * 10 + lane] = ey / sm;
}

extern "C" void kernel_launch(void* const* d_in, const int* in_sizes, int n_in,
                              void* d_out, int out_size, void* d_ws, size_t ws_size,
                              hipStream_t stream) {
    const float* x = (const float*)d_in[0];
    const int* rows = (const int*)d_in[1];
    const int* cols = (const int*)d_in[2];
    const float* vals = (const float*)d_in[3];
    const int* batch = (const int*)d_in[4];
    const float* W1 = (const float*)d_in[5];
    const float* b1 = (const float*)d_in[6];
    const float* W2 = (const float*)d_in[7];
    const float* b2 = (const float*)d_in[8];
    const float* W3 = (const float*)d_in[9];
    const float* b3 = (const float*)d_in[10];
    const float* Wl = (const float*)d_in[11];
    const float* bl = (const float*)d_in[12];
    float* out = (float*)d_out;

    const int N = in_sizes[4];   // n_nodes (<= 131072 for MAXK/packing)
    const int E = in_sizes[1];   // n_edges
    const int G = out_size / 10; // n_graphs
    const int K = (N + BROWS - 1) >> BSHIFT;

    char* p = (char*)d_ws;
    size_t off = 0;
    auto alloc = [&](size_t bytes) -> void* {
        off = (off + 255) & ~(size_t)255;
        void* r = (void*)(p + off);
        off += bytes;
        return r;
    };
    size_t featF = (size_t)N * 64 * 4;
    int* bhist = (int*)alloc(MAXK * 4);
    int* bstart = (int*)alloc((MAXK + 1) * 4);
    int* bcur = (int*)alloc(MAXK * 16 * 4);
    int2* pk = (int2*)alloc((size_t)E * 8);
    unsigned short* Zb = (unsigned short*)alloc((size_t)N * 64 * 2);
    float* x1 = (float*)alloc(featF);
    float* x2 = (float*)alloc(featF);
    float* x3 = (float*)alloc(featF);
    float* sums = (float*)alloc((size_t)G * 64 * 4);
    int* cnts = (int*)alloc((size_t)G * 4);

    hipMemsetAsync(bhist, 0, MAXK * 4, stream);
    hipMemsetAsync(sums, 0, (size_t)G * 64 * 4, stream);
    hipMemsetAsync(cnts, 0, (size_t)G * 4, stream);

    int cb = (E + CHUNK - 1) / CHUNK;
    bhist_k<<<cb, 256, 0, stream>>>(rows, bhist, E);
    bscan_k<<<1, MAXK, 0, stream>>>(bhist, bstart, bcur, K, E);
    binpass_k<<<cb, 256, 0, stream>>>(rows, cols, vals, bcur, pk, E);

    int rb = (N + 3) / 4;  // wave-per-row blocks
    dense5_k<<<rb, 256, 0, stream>>>(x, W1, Zb, N);
    spmm_push_k<<<K, 512, 0, stream>>>(bstart, pk, Zb, b1, x1, N);
    dense64_k<<<rb, 256, 0, stream>>>(x1, W2, Zb, N);
    spmm_push_k<<<K, 512, 0, stream>>>(bstart, pk, Zb, b2, x2, N);
    dense64_k<<<rb, 256, 0, stream>>>(x2, W3, Zb, N);
    spmm_push_k<<<K, 512, 0, stream>>>(bstart, pk, Zb, b3, x3, N);

    int pw = (N + 63) / 64;
    pool_k<<<(pw + 3) / 4, 256, 0, stream>>>(x1, x2, x3, batch, sums, cnts, N);
    final_k<<<(G + 3) / 4, 256, 0, stream>>>(sums, cnts, Wl, bl, out, G);
}

// Round 5
// 674.958 us; speedup vs baseline: 6.5540x; 6.5540x over previous
//
#include <hip/hip_runtime.h>

// GCN3: 3x (COO spmm -> Linear(64) -> ReLU), segment-mean pool, softmax head.
// relu(spmm(X)@W + b) == relu(spmm(X@W) + b): dense transform first, then
// PULL-spmm (wave per row, 8 gathers in flight) from bf16 Z.
// CSR build: LDS-staged binpass into 256-row buckets (write-combined), then
// per-bucket counting sort (single-CU 64KB window -> L2-combined scatter)
// that emits row-sorted edges + per-row rp in one kernel.

#define BSHIFT 8
#define BROWS  (1 << BSHIFT)   // 256 rows per bucket
#define MAXK   512             // supports N <= 131072
#define CHUNK  4096            // edges per binpass block

__device__ inline unsigned short f2bf(float f) {  // RNE bf16
    unsigned u = __float_as_uint(f);
    u += 0x7fffu + ((u >> 16) & 1u);
    return (unsigned short)(u >> 16);
}
__device__ inline float bf2f(unsigned short h) {
    return __uint_as_float((unsigned)h << 16);
}

// Per-block LDS histogram of bucket ids -> global bucket counts.
__global__ __launch_bounds__(512) void bhist_k(const int* __restrict__ rows,
                                               int* __restrict__ bhist, int E) {
    __shared__ int h[MAXK];
    int tx = threadIdx.x;
    h[tx] = 0;
    __syncthreads();
    int e0 = blockIdx.x * CHUNK, ee = min(e0 + CHUNK, E);
    for (int e = e0 + tx; e < ee; e += 512) atomicAdd(&h[rows[e] >> BSHIFT], 1);
    __syncthreads();
    if (h[tx]) atomicAdd(&bhist[tx], h[tx]);
}

// Exclusive scan of bucket counts (single block); init padded cursors; rp[N]=E.
__global__ __launch_bounds__(MAXK) void bscan_k(const int* __restrict__ bhist,
                                                int* __restrict__ bstart,
                                                int* __restrict__ bcur,
                                                int* __restrict__ rp,
                                                int K, int E, int N) {
    __shared__ int s[MAXK];
    int tx = threadIdx.x;
    int v = (tx < K) ? bhist[tx] : 0;
    s[tx] = v;
    __syncthreads();
    for (int off = 1; off < MAXK; off <<= 1) {
        int t = (tx >= off) ? s[tx - off] : 0;
        __syncthreads();
        s[tx] += t;
        __syncthreads();
    }
    if (tx < K) {
        bstart[tx] = s[tx] - v;
        bcur[tx * 16] = s[tx] - v;  // 1 cursor per 64B line
    }
    if (tx == K - 1) bstart[K] = E;
    if (tx == 0) rp[N] = E;
}

// Bin edges by 256-row bucket, staged in LDS so global writes are contiguous
// single-CU bursts (write-combining). Record: x=(col<<8)|(row&255), y=val.
__global__ __launch_bounds__(512) void binpass_k(
    const int* __restrict__ rows, const int* __restrict__ cols,
    const float* __restrict__ vals, int* __restrict__ bcur,
    int2* __restrict__ pk, int E) {
    __shared__ int h[MAXK], base[MAXK], gbase[MAXK], lcnt[MAXK];
    __shared__ int2 st[CHUNK];
    int tx = threadIdx.x;
    h[tx] = 0;
    __syncthreads();
    int e0 = blockIdx.x * CHUNK, ee = min(e0 + CHUNK, E);
    for (int e = e0 + tx; e < ee; e += 512) atomicAdd(&h[rows[e] >> BSHIFT], 1);
    __syncthreads();
    int v = h[tx];
    lcnt[tx] = v;  // scan buffer (inclusive)
    __syncthreads();
    for (int off = 1; off < MAXK; off <<= 1) {
        int t = (tx >= off) ? lcnt[tx - off] : 0;
        __syncthreads();
        lcnt[tx] += t;
        __syncthreads();
    }
    base[tx] = lcnt[tx] - v;
    if (v) gbase[tx] = atomicAdd(&bcur[tx * 16], v);
    lcnt[tx] = 0;
    __syncthreads();
    for (int e = e0 + tx; e < ee; e += 512) {
        int r = rows[e];
        int b = r >> BSHIFT;
        int p = base[b] + atomicAdd(&lcnt[b], 1);
        st[p] = make_int2((cols[e] << BSHIFT) | (r & (BROWS - 1)),
                          __float_as_int(vals[e]));
    }
    __syncthreads();
    // flush contiguous per-bucket runs, wave-parallel
    int lane = tx & 63, wid = tx >> 6;
    for (int b = wid; b < MAXK; b += 8) {
        int cnt = h[b];
        if (!cnt) continue;
        int lb = base[b], gb = gbase[b];
        for (int i = lane; i < cnt; i += 64) pk[gb + i] = st[lb + i];
    }
}

// Per-bucket counting sort: one block per bucket. LDS hist over 256 rows,
// scan -> rp for these rows, then local scatter into the bucket's contiguous
// epk window (single CU -> lines assembled in its L2 before writeback).
// Output record: (col, val bits), row-grouped; rp gives row extents.
__global__ __launch_bounds__(512) void sort_k(
    const int* __restrict__ bstart, const int2* __restrict__ pk,
    int* __restrict__ rp, int2* __restrict__ epk, int n) {
    __shared__ int hist[BROWS], cur[BROWS];
    int tx = threadIdx.x;
    int b = blockIdx.x;
    int row0 = b << BSHIFT;
    int s = bstart[b], e = bstart[b + 1];
    if (tx < BROWS) hist[tx] = 0;
    __syncthreads();
    for (int j = s + tx; j < e; j += 512)
        atomicAdd(&hist[pk[j].x & (BROWS - 1)], 1);
    __syncthreads();
    int v = (tx < BROWS) ? hist[tx] : 0;
    for (int off = 1; off < BROWS; off <<= 1) {
        int t = (tx >= off && tx < BROWS) ? hist[tx - off] : 0;
        __syncthreads();
        if (tx < BROWS) hist[tx] += t;
        __syncthreads();
    }
    if (tx < BROWS) {
        int excl = hist[tx] - v;
        cur[tx] = excl;
        if (row0 + tx < n) rp[row0 + tx] = s + excl;
    }
    __syncthreads();
    for (int j = s + tx; j < e; j += 512) {
        int2 rec = pk[j];
        int r = rec.x & (BROWS - 1);
        int q = atomicAdd(&cur[r], 1);
        epk[s + q] = make_int2((int)((unsigned)rec.x >> BSHIFT), rec.y);
    }
}

// Z0 = bf16(X @ W1), X:[n,5]. Wave per row, lane = out dim.
__global__ __launch_bounds__(256) void dense5_k(
    const float* __restrict__ X, const float* __restrict__ W,
    unsigned short* __restrict__ Zb, int n) {
    int lane = threadIdx.x & 63;
    int row = (blockIdx.x * blockDim.x + threadIdx.x) >> 6;
    if (row >= n) return;
    float w0 = W[lane], w1 = W[64 + lane], w2 = W[128 + lane],
          w3 = W[192 + lane], w4 = W[256 + lane];
    float xv = (lane < 5) ? X[(size_t)row * 5 + lane] : 0.f;
    float y = __shfl(xv, 0, 64) * w0;
    y = fmaf(__shfl(xv, 1, 64), w1, y);
    y = fmaf(__shfl(xv, 2, 64), w2, y);
    y = fmaf(__shfl(xv, 3, 64), w3, y);
    y = fmaf(__shfl(xv, 4, 64), w4, y);
    Zb[(size_t)row * 64 + lane] = f2bf(y);
}

// Zb = bf16(X @ W), X:[n,64] fp32, W in LDS. Wave per row, lane = out dim.
__global__ __launch_bounds__(256) void dense64_k(
    const float* __restrict__ X, const float* __restrict__ W,
    unsigned short* __restrict__ Zb, int n) {
    __shared__ float Ws[64 * 64];
    int tx = threadIdx.x, lane = tx & 63;
    for (int i = tx; i < 4096; i += 256) Ws[i] = W[i];
    __syncthreads();
    int row = (blockIdx.x * blockDim.x + tx) >> 6;
    if (row >= n) return;
    const float4* xr = (const float4*)(X + (size_t)row * 64);
    float y = 0.f;
#pragma unroll
    for (int k4 = 0; k4 < 16; ++k4) {
        float4 xv = xr[k4];  // wave-uniform broadcast
        int k = k4 * 4;
        y = fmaf(xv.x, Ws[(k + 0) * 64 + lane], y);
        y = fmaf(xv.y, Ws[(k + 1) * 64 + lane], y);
        y = fmaf(xv.z, Ws[(k + 2) * 64 + lane], y);
        y = fmaf(xv.w, Ws[(k + 3) * 64 + lane], y);
    }
    Zb[(size_t)row * 64 + lane] = f2bf(y);
}

// xout[row] = relu(sum_e v_e * Zb[col_e] + b), fp32 accumulate.
// Wave per row, lane = dim; 128B coalesced bf16 gathers; 8 independent
// accumulators keep 8 gathers in flight per wave (MLP is the bottleneck).
__global__ __launch_bounds__(256) void spmm_relu_k(
    const int* __restrict__ rp, const int2* __restrict__ epack,
    const unsigned short* __restrict__ Zb, const float* __restrict__ b,
    float* __restrict__ xout, int n) {
    int lane = threadIdx.x & 63;
    int row = (blockIdx.x * blockDim.x + threadIdx.x) >> 6;
    if (row >= n) return;
    int s = rp[row], e = rp[row + 1];
    float t0 = 0.f, t1 = 0.f, t2 = 0.f, t3 = 0.f,
          t4 = 0.f, t5 = 0.f, t6 = 0.f, t7 = 0.f;
    int j = s;
    for (; j + 8 <= e; j += 8) {
        int2 c0 = epack[j + 0], c1 = epack[j + 1], c2 = epack[j + 2],
             c3 = epack[j + 3], c4 = epack[j + 4], c5 = epack[j + 5],
             c6 = epack[j + 6], c7 = epack[j + 7];
        float z0 = bf2f(Zb[(size_t)c0.x * 64 + lane]);
        float z1 = bf2f(Zb[(size_t)c1.x * 64 + lane]);
        float z2 = bf2f(Zb[(size_t)c2.x * 64 + lane]);
        float z3 = bf2f(Zb[(size_t)c3.x * 64 + lane]);
        float z4 = bf2f(Zb[(size_t)c4.x * 64 + lane]);
        float z5 = bf2f(Zb[(size_t)c5.x * 64 + lane]);
        float z6 = bf2f(Zb[(size_t)c6.x * 64 + lane]);
        float z7 = bf2f(Zb[(size_t)c7.x * 64 + lane]);
        t0 = fmaf(__int_as_float(c0.y), z0, t0);
        t1 = fmaf(__int_as_float(c1.y), z1, t1);
        t2 = fmaf(__int_as_float(c2.y), z2, t2);
        t3 = fmaf(__int_as_float(c3.y), z3, t3);
        t4 = fmaf(__int_as_float(c4.y), z4, t4);
        t5 = fmaf(__int_as_float(c5.y), z5, t5);
        t6 = fmaf(__int_as_float(c6.y), z6, t6);
        t7 = fmaf(__int_as_float(c7.y), z7, t7);
    }
    for (; j < e; ++j) {
        int2 cv = epack[j];
        float z = bf2f(Zb[(size_t)cv.x * 64 + lane]);
        t0 = fmaf(__int_as_float(cv.y), z, t0);
    }
    float t = ((t0 + t1) + (t2 + t3)) + ((t4 + t5) + (t6 + t7));
    xout[(size_t)row * 64 + lane] = fmaxf(t + b[lane], 0.f);
}

// Pool: batch sorted -> run-length accumulate 64 nodes per wave, one
// atomicAdd per segment boundary per lane.
__global__ void pool_k(const float* __restrict__ x1, const float* __restrict__ x2,
                       const float* __restrict__ x3, const int* __restrict__ batch,
                       float* __restrict__ sums, int* __restrict__ cnts, int n) {
    int lane = threadIdx.x & 63;
    int w = (blockIdx.x * blockDim.x + threadIdx.x) >> 6;
    int node0 = w * 64;
    if (node0 >= n) return;
    int cur = batch[node0];
    float acc = 0.f;
    int cnt = 0;
    int end = min(node0 + 64, n);
    for (int nd = node0; nd < end; ++nd) {
        int bg = batch[nd];  // wave-uniform
        if (bg != cur) {
            atomicAdd(&sums[(size_t)cur * 64 + lane], acc);
            if (lane == 0) atomicAdd(&cnts[cur], cnt);
            acc = 0.f;
            cnt = 0;
            cur = bg;
        }
        size_t o = (size_t)nd * 64 + lane;
        acc += x1[o] + x2[o] + x3[o];
        cnt++;
    }
    atomicAdd(&sums[(size_t)cur * 64 + lane], acc);
    if (lane == 0) atomicAdd(&cnts[cur], cnt);
}

// Head: pooled = sums/(3*cnt); out = softmax(pooled @ Wl + bl). Wave per graph.
__global__ void final_k(const float* __restrict__ sums, const int* __restrict__ cnts,
                        const float* __restrict__ Wl, const float* __restrict__ bl,
                        float* __restrict__ out, int G) {
    int lane = threadIdx.x & 63;
    int g = (blockIdx.x * blockDim.x + threadIdx.x) >> 6;
    if (g >= G) return;
    float c = (float)max(cnts[g], 1);
    float s = sums[(size_t)g * 64 + lane] / (3.f * c);
    float y = (lane < 10) ? bl[lane] : -1e30f;
    for (int k = 0; k < 64; ++k) {
        float sk = __shfl(s, k, 64);
        if (lane < 10) y = fmaf(sk, Wl[k * 10 + lane], y);
    }
    float m = y;
#pragma unroll
    for (int off = 8; off; off >>= 1) m = fmaxf(m, __shfl_xor(m, off, 16));
    float ey = (lane < 10) ? __expf(y - m) : 0.f;
    float sm = ey;
#pragma unroll
    for (int off = 8; off; off >>= 1) sm += __shfl_xor(sm, off, 16);
    if (lane < 10) out[(size_t)g * 10 + lane] = ey / sm;
}

extern "C" void kernel_launch(void* const* d_in, const int* in_sizes, int n_in,
                              void* d_out, int out_size, void* d_ws, size_t ws_size,
                              hipStream_t stream) {
    const float* x = (const float*)d_in[0];
    const int* rows = (const int*)d_in[1];
    const int* cols = (const int*)d_in[2];
    const float* vals = (const float*)d_in[3];
    const int* batch = (const int*)d_in[4];
    const float* W1 = (const float*)d_in[5];
    const float* b1 = (const float*)d_in[6];
    const float* W2 = (const float*)d_in[7];
    const float* b2 = (const float*)d_in[8];
    const float* W3 = (const float*)d_in[9];
    const float* b3 = (const float*)d_in[10];
    const float* Wl = (const float*)d_in[11];
    const float* bl = (const float*)d_in[12];
    float* out = (float*)d_out;

    const int N = in_sizes[4];   // n_nodes (<= 131072 for MAXK/packing)
    const int E = in_sizes[1];   // n_edges
    const int G = out_size / 10; // n_graphs
    const int K = (N + BROWS - 1) >> BSHIFT;

    char* p = (char*)d_ws;
    size_t off = 0;
    auto alloc = [&](size_t bytes) -> void* {
        off = (off + 255) & ~(size_t)255;
        void* r = (void*)(p + off);
        off += bytes;
        return r;
    };
    size_t featF = (size_t)N * 64 * 4;
    int* bhist = (int*)alloc(MAXK * 4);
    int* bstart = (int*)alloc((MAXK + 1) * 4);
    int* bcur = (int*)alloc(MAXK * 16 * 4);
    int* rp = (int*)alloc((size_t)(N + 1) * 4);
    // pk (bucketed, pre-sort) is dead after sort_k; alias with x3 (written
    // only by the layer-3 spmm, far after sort_k).
    void* regP = alloc((size_t)E * 8 > featF ? (size_t)E * 8 : featF);
    int2* epk = (int2*)alloc((size_t)E * 8);      // row-sorted edges (col, val)
    unsigned short* Zb = (unsigned short*)alloc((size_t)N * 64 * 2);
    float* x1 = (float*)alloc(featF);
    float* x2 = (float*)alloc(featF);
    float* sums = (float*)alloc((size_t)G * 64 * 4);
    int* cnts = (int*)alloc((size_t)G * 4);

    int2* pk = (int2*)regP;
    float* x3 = (float*)regP;

    hipMemsetAsync(bhist, 0, MAXK * 4, stream);
    hipMemsetAsync(sums, 0, (size_t)G * 64 * 4, stream);
    hipMemsetAsync(cnts, 0, (size_t)G * 4, stream);

    int cb = (E + CHUNK - 1) / CHUNK;
    bhist_k<<<cb, 512, 0, stream>>>(rows, bhist, E);
    bscan_k<<<1, MAXK, 0, stream>>>(bhist, bstart, bcur, rp, K, E, N);
    binpass_k<<<cb, 512, 0, stream>>>(rows, cols, vals, bcur, pk, E);
    sort_k<<<K, 512, 0, stream>>>(bstart, pk, rp, epk, N);

    int rb = (N + 3) / 4;  // wave-per-row blocks
    dense5_k<<<rb, 256, 0, stream>>>(x, W1, Zb, N);
    spmm_relu_k<<<rb, 256, 0, stream>>>(rp, epk, Zb, b1, x1, N);
    dense64_k<<<rb, 256, 0, stream>>>(x1, W2, Zb, N);
    spmm_relu_k<<<rb, 256, 0, stream>>>(rp, epk, Zb, b2, x2, N);
    dense64_k<<<rb, 256, 0, stream>>>(x2, W3, Zb, N);
    spmm_relu_k<<<rb, 256, 0, stream>>>(rp, epk, Zb, b3, x3, N);

    int pw = (N + 63) / 64;
    pool_k<<<(pw + 3) / 4, 256, 0, stream>>>(x1, x2, x3, batch, sums, cnts, N);
    final_k<<<(G + 3) / 4, 256, 0, stream>>>(sums, cnts, Wl, bl, out, G);
}

// Round 6
// 641.195 us; speedup vs baseline: 6.8991x; 1.0527x over previous
//
#include <hip/hip_runtime.h>

// GCN3: 3x (COO spmm -> Linear(64) -> ReLU), segment-mean pool, softmax head.
// relu(spmm(X)@W + b) == relu(spmm(X@W) + b): dense transform first, then
// PULL-spmm (wave per row, lane = dim, 16 gathers in flight) from fp8 Z
// (e4m3, 64B/row -> halves gather bytes vs bf16; fp32 accumulate).
// CSR build: LDS-staged binpass into 512-row buckets (write-combined bursts),
// then per-bucket counting sort emitting row-sorted edges + rp.

#define BSHIFT 9
#define BROWS  (1 << BSHIFT)   // 512 rows per bucket
#define MAXK   256             // supports N <= 131072
#define CHUNK  6144            // edges per binpass/bhist block

__device__ inline unsigned char f2q(float f) {  // fp8 e4m3 RNE
    unsigned p = __builtin_amdgcn_cvt_pk_fp8_f32(f, f, 0u, false);
    return (unsigned char)(p & 0xffu);
}
__device__ inline float q2f(unsigned char q) {
    return __builtin_amdgcn_cvt_f32_fp8((unsigned)q, 0);
}

// Per-block LDS histogram of bucket ids -> global bucket counts.
__global__ __launch_bounds__(512) void bhist_k(const int* __restrict__ rows,
                                               int* __restrict__ bhist, int E) {
    __shared__ int h[MAXK];
    int tx = threadIdx.x;
    if (tx < MAXK) h[tx] = 0;
    __syncthreads();
    int e0 = blockIdx.x * CHUNK, ee = min(e0 + CHUNK, E);
    for (int e = e0 + tx; e < ee; e += 512) atomicAdd(&h[rows[e] >> BSHIFT], 1);
    __syncthreads();
    if (tx < MAXK && h[tx]) atomicAdd(&bhist[tx], h[tx]);
}

// Exclusive scan of bucket counts (single block); init padded cursors; rp[N]=E.
__global__ __launch_bounds__(MAXK) void bscan_k(const int* __restrict__ bhist,
                                                int* __restrict__ bstart,
                                                int* __restrict__ bcur,
                                                int* __restrict__ rp,
                                                int K, int E, int N) {
    __shared__ int s[MAXK];
    int tx = threadIdx.x;
    int v = (tx < K) ? bhist[tx] : 0;
    s[tx] = v;
    __syncthreads();
    for (int off = 1; off < MAXK; off <<= 1) {
        int t = (tx >= off) ? s[tx - off] : 0;
        __syncthreads();
        s[tx] += t;
        __syncthreads();
    }
    if (tx < K) {
        bstart[tx] = s[tx] - v;
        bcur[tx * 16] = s[tx] - v;  // 1 cursor per 64B line
    }
    if (tx == K - 1) bstart[K] = E;
    if (tx == 0) rp[N] = E;
}

// Bin edges by 512-row bucket, staged in LDS so global writes are ~31-edge
// (250B) single-CU bursts. Record: x=(col<<9)|(row&511), y=val bits.
__global__ __launch_bounds__(512) void binpass_k(
    const int* __restrict__ rows, const int* __restrict__ cols,
    const float* __restrict__ vals, int* __restrict__ bcur,
    int2* __restrict__ pk, int E) {
    __shared__ int h[MAXK], base[MAXK], gbase[MAXK], lcnt[MAXK];
    __shared__ int2 st[CHUNK];  // 48 KB
    int tx = threadIdx.x;
    if (tx < MAXK) h[tx] = 0;
    __syncthreads();
    int e0 = blockIdx.x * CHUNK, ee = min(e0 + CHUNK, E);
    for (int e = e0 + tx; e < ee; e += 512) atomicAdd(&h[rows[e] >> BSHIFT], 1);
    __syncthreads();
    int v = (tx < MAXK) ? h[tx] : 0;
    if (tx < MAXK) lcnt[tx] = v;  // scan buffer
    __syncthreads();
    for (int off = 1; off < MAXK; off <<= 1) {
        int t = (tx >= off && tx < MAXK) ? lcnt[tx - off] : 0;
        __syncthreads();
        if (tx < MAXK) lcnt[tx] += t;
        __syncthreads();
    }
    if (tx < MAXK) {
        base[tx] = lcnt[tx] - v;
        if (v) gbase[tx] = atomicAdd(&bcur[tx * 16], v);
        lcnt[tx] = 0;
    }
    __syncthreads();
    for (int e = e0 + tx; e < ee; e += 512) {
        int r = rows[e];
        int b = r >> BSHIFT;
        int p = base[b] + atomicAdd(&lcnt[b], 1);
        st[p] = make_int2((cols[e] << BSHIFT) | (r & (BROWS - 1)),
                          __float_as_int(vals[e]));
    }
    __syncthreads();
    // flush contiguous per-bucket runs, wave-parallel
    int lane = tx & 63, wid = tx >> 6;
    for (int b = wid; b < MAXK; b += 8) {
        int cnt = h[b];
        if (!cnt) continue;
        int lb = base[b], gb = gbase[b];
        for (int i = lane; i < cnt; i += 64) pk[gb + i] = st[lb + i];
    }
}

// Per-bucket counting sort: one block per bucket. LDS hist over 512 rows,
// scan -> rp, then local scatter into the bucket's contiguous epk window
// (single-CU ~130KB window -> L2-combined). Output record: (col, val bits).
__global__ __launch_bounds__(512) void sort_k(
    const int* __restrict__ bstart, const int2* __restrict__ pk,
    int* __restrict__ rp, int2* __restrict__ epk, int n) {
    __shared__ int hist[BROWS], cur[BROWS];
    int tx = threadIdx.x;
    int b = blockIdx.x;
    int row0 = b << BSHIFT;
    int s = bstart[b], e = bstart[b + 1];
    hist[tx] = 0;
    __syncthreads();
    for (int j = s + tx; j < e; j += 512)
        atomicAdd(&hist[pk[j].x & (BROWS - 1)], 1);
    __syncthreads();
    int v = hist[tx];
    for (int off = 1; off < BROWS; off <<= 1) {
        int t = (tx >= off) ? hist[tx - off] : 0;
        __syncthreads();
        hist[tx] += t;
        __syncthreads();
    }
    int excl = hist[tx] - v;
    cur[tx] = excl;
    if (row0 + tx < n) rp[row0 + tx] = s + excl;
    __syncthreads();
    for (int j = s + tx; j < e; j += 512) {
        int2 rec = pk[j];
        int r = rec.x & (BROWS - 1);
        int q = atomicAdd(&cur[r], 1);
        epk[s + q] = make_int2((int)((unsigned)rec.x >> BSHIFT), rec.y);
    }
}

// Zq = fp8(X @ W1), X:[n,5]. Wave per row, lane = out dim.
__global__ __launch_bounds__(256) void dense5_k(
    const float* __restrict__ X, const float* __restrict__ W,
    unsigned char* __restrict__ Zq, int n) {
    int lane = threadIdx.x & 63;
    int row = (blockIdx.x * blockDim.x + threadIdx.x) >> 6;
    if (row >= n) return;
    float w0 = W[lane], w1 = W[64 + lane], w2 = W[128 + lane],
          w3 = W[192 + lane], w4 = W[256 + lane];
    float xv = (lane < 5) ? X[(size_t)row * 5 + lane] : 0.f;
    float y = __shfl(xv, 0, 64) * w0;
    y = fmaf(__shfl(xv, 1, 64), w1, y);
    y = fmaf(__shfl(xv, 2, 64), w2, y);
    y = fmaf(__shfl(xv, 3, 64), w3, y);
    y = fmaf(__shfl(xv, 4, 64), w4, y);
    Zq[(size_t)row * 64 + lane] = f2q(y);
}

// Zq = fp8(X @ W), X:[n,64] fp32, W in LDS. Wave per row, lane = out dim.
__global__ __launch_bounds__(256) void dense64_k(
    const float* __restrict__ X, const float* __restrict__ W,
    unsigned char* __restrict__ Zq, int n) {
    __shared__ float Ws[64 * 64];
    int tx = threadIdx.x, lane = tx & 63;
    for (int i = tx; i < 4096; i += 256) Ws[i] = W[i];
    __syncthreads();
    int row = (blockIdx.x * blockDim.x + tx) >> 6;
    if (row >= n) return;
    const float4* xr = (const float4*)(X + (size_t)row * 64);
    float y = 0.f;
#pragma unroll
    for (int k4 = 0; k4 < 16; ++k4) {
        float4 xv = xr[k4];  // wave-uniform broadcast
        int k = k4 * 4;
        y = fmaf(xv.x, Ws[(k + 0) * 64 + lane], y);
        y = fmaf(xv.y, Ws[(k + 1) * 64 + lane], y);
        y = fmaf(xv.z, Ws[(k + 2) * 64 + lane], y);
        y = fmaf(xv.w, Ws[(k + 3) * 64 + lane], y);
    }
    Zq[(size_t)row * 64 + lane] = f2q(y);
}

// xout[row] = relu(sum_e v_e * Zq[col_e] + b), fp32 accumulate.
// Wave per row, lane = dim; 64B coalesced fp8 gathers, 32-bit offsets,
// 16 -> 8 -> scalar unroll cascade keeps up to 16 gathers in flight.
__global__ __launch_bounds__(256) void spmm_relu_k(
    const int* __restrict__ rp, const int2* __restrict__ epk,
    const unsigned char* __restrict__ Zq, const float* __restrict__ b,
    float* __restrict__ xout, int n) {
    int lane = threadIdx.x & 63;
    int row = (blockIdx.x * blockDim.x + threadIdx.x) >> 6;
    if (row >= n) return;
    int s = rp[row], e = rp[row + 1];
    float t[8] = {0.f, 0.f, 0.f, 0.f, 0.f, 0.f, 0.f, 0.f};
    int j = s;
    for (; j + 16 <= e; j += 16) {
        int2 c[16];
#pragma unroll
        for (int i = 0; i < 16; ++i) c[i] = epk[j + i];
        float z[16];
#pragma unroll
        for (int i = 0; i < 16; ++i)
            z[i] = q2f(Zq[((unsigned)c[i].x << 6) + (unsigned)lane]);
#pragma unroll
        for (int i = 0; i < 16; ++i)
            t[i & 7] = fmaf(__int_as_float(c[i].y), z[i], t[i & 7]);
    }
    for (; j + 8 <= e; j += 8) {
        int2 c[8];
#pragma unroll
        for (int i = 0; i < 8; ++i) c[i] = epk[j + i];
        float z[8];
#pragma unroll
        for (int i = 0; i < 8; ++i)
            z[i] = q2f(Zq[((unsigned)c[i].x << 6) + (unsigned)lane]);
#pragma unroll
        for (int i = 0; i < 8; ++i)
            t[i] = fmaf(__int_as_float(c[i].y), z[i], t[i]);
    }
    for (; j < e; ++j) {
        int2 cv = epk[j];
        float z = q2f(Zq[((unsigned)cv.x << 6) + (unsigned)lane]);
        t[0] = fmaf(__int_as_float(cv.y), z, t[0]);
    }
    float tt = ((t[0] + t[1]) + (t[2] + t[3])) + ((t[4] + t[5]) + (t[6] + t[7]));
    xout[(size_t)row * 64 + lane] = fmaxf(tt + b[lane], 0.f);
}

// Layer-3 spmm with fused h = x3 + x1 + x2 (pool then averages h/(3*cnt)).
__global__ __launch_bounds__(256) void spmm_relu3_k(
    const int* __restrict__ rp, const int2* __restrict__ epk,
    const unsigned char* __restrict__ Zq, const float* __restrict__ b,
    const float* __restrict__ x1, const float* __restrict__ x2,
    float* __restrict__ h, int n) {
    int lane = threadIdx.x & 63;
    int row = (blockIdx.x * blockDim.x + threadIdx.x) >> 6;
    if (row >= n) return;
    int s = rp[row], e = rp[row + 1];
    float t[8] = {0.f, 0.f, 0.f, 0.f, 0.f, 0.f, 0.f, 0.f};
    int j = s;
    for (; j + 16 <= e; j += 16) {
        int2 c[16];
#pragma unroll
        for (int i = 0; i < 16; ++i) c[i] = epk[j + i];
        float z[16];
#pragma unroll
        for (int i = 0; i < 16; ++i)
            z[i] = q2f(Zq[((unsigned)c[i].x << 6) + (unsigned)lane]);
#pragma unroll
        for (int i = 0; i < 16; ++i)
            t[i & 7] = fmaf(__int_as_float(c[i].y), z[i], t[i & 7]);
    }
    for (; j + 8 <= e; j += 8) {
        int2 c[8];
#pragma unroll
        for (int i = 0; i < 8; ++i) c[i] = epk[j + i];
        float z[8];
#pragma unroll
        for (int i = 0; i < 8; ++i)
            z[i] = q2f(Zq[((unsigned)c[i].x << 6) + (unsigned)lane]);
#pragma unroll
        for (int i = 0; i < 8; ++i)
            t[i] = fmaf(__int_as_float(c[i].y), z[i], t[i]);
    }
    for (; j < e; ++j) {
        int2 cv = epk[j];
        float z = q2f(Zq[((unsigned)cv.x << 6) + (unsigned)lane]);
        t[0] = fmaf(__int_as_float(cv.y), z, t[0]);
    }
    float tt = ((t[0] + t[1]) + (t[2] + t[3])) + ((t[4] + t[5]) + (t[6] + t[7]));
    size_t o = (size_t)row * 64 + lane;
    h[o] = fmaxf(tt + b[lane], 0.f) + x1[o] + x2[o];
}

// Pool: batch sorted -> run-length accumulate 64 nodes per wave, one
// atomicAdd per segment boundary per lane. h already = x1+x2+x3.
__global__ void pool_k(const float* __restrict__ h, const int* __restrict__ batch,
                       float* __restrict__ sums, int* __restrict__ cnts, int n) {
    int lane = threadIdx.x & 63;
    int w = (blockIdx.x * blockDim.x + threadIdx.x) >> 6;
    int node0 = w * 64;
    if (node0 >= n) return;
    int cur = batch[node0];
    float acc = 0.f;
    int cnt = 0;
    int end = min(node0 + 64, n);
    for (int nd = node0; nd < end; ++nd) {
        int bg = batch[nd];  // wave-uniform
        if (bg != cur) {
            atomicAdd(&sums[(size_t)cur * 64 + lane], acc);
            if (lane == 0) atomicAdd(&cnts[cur], cnt);
            acc = 0.f;
            cnt = 0;
            cur = bg;
        }
        acc += h[(size_t)nd * 64 + lane];
        cnt++;
    }
    atomicAdd(&sums[(size_t)cur * 64 + lane], acc);
    if (lane == 0) atomicAdd(&cnts[cur], cnt);
}

// Head: pooled = sums/(3*cnt); out = softmax(pooled @ Wl + bl). Wave per graph.
__global__ void final_k(const float* __restrict__ sums, const int* __restrict__ cnts,
                        const float* __restrict__ Wl, const float* __restrict__ bl,
                        float* __restrict__ out, int G) {
    int lane = threadIdx.x & 63;
    int g = (blockIdx.x * blockDim.x + threadIdx.x) >> 6;
    if (g >= G) return;
    float c = (float)max(cnts[g], 1);
    float s = sums[(size_t)g * 64 + lane] / (3.f * c);
    float y = (lane < 10) ? bl[lane] : -1e30f;
    for (int k = 0; k < 64; ++k) {
        float sk = __shfl(s, k, 64);
        if (lane < 10) y = fmaf(sk, Wl[k * 10 + lane], y);
    }
    float m = y;
#pragma unroll
    for (int off = 8; off; off >>= 1) m = fmaxf(m, __shfl_xor(m, off, 16));
    float ey = (lane < 10) ? __expf(y - m) : 0.f;
    float sm = ey;
#pragma unroll
    for (int off = 8; off; off >>= 1) sm += __shfl_xor(sm, off, 16);
    if (lane < 10) out[(size_t)g * 10 + lane] = ey / sm;
}

extern "C" void kernel_launch(void* const* d_in, const int* in_sizes, int n_in,
                              void* d_out, int out_size, void* d_ws, size_t ws_size,
                              hipStream_t stream) {
    const float* x = (const float*)d_in[0];
    const int* rows = (const int*)d_in[1];
    const int* cols = (const int*)d_in[2];
    const float* vals = (const float*)d_in[3];
    const int* batch = (const int*)d_in[4];
    const float* W1 = (const float*)d_in[5];
    const float* b1 = (const float*)d_in[6];
    const float* W2 = (const float*)d_in[7];
    const float* b2 = (const float*)d_in[8];
    const float* W3 = (const float*)d_in[9];
    const float* b3 = (const float*)d_in[10];
    const float* Wl = (const float*)d_in[11];
    const float* bl = (const float*)d_in[12];
    float* out = (float*)d_out;

    const int N = in_sizes[4];   // n_nodes (<= 131072)
    const int E = in_sizes[1];   // n_edges
    const int G = out_size / 10; // n_graphs
    const int K = (N + BROWS - 1) >> BSHIFT;

    char* p = (char*)d_ws;
    size_t off = 0;
    auto alloc = [&](size_t bytes) -> void* {
        off = (off + 255) & ~(size_t)255;
        void* r = (void*)(p + off);
        off += bytes;
        return r;
    };
    size_t featF = (size_t)N * 64 * 4;
    int* bhist = (int*)alloc(MAXK * 4);
    int* bstart = (int*)alloc((MAXK + 1) * 4);
    int* bcur = (int*)alloc(MAXK * 16 * 4);
    int* rp = (int*)alloc((size_t)(N + 1) * 4);
    // pk (bucketed, pre-sort) is dead after sort_k; alias with h (written
    // only by the layer-3 spmm, far after sort_k).
    void* regP = alloc((size_t)E * 8 > featF ? (size_t)E * 8 : featF);
    int2* epk = (int2*)alloc((size_t)E * 8);      // row-sorted edges (col, val)
    unsigned char* Zq = (unsigned char*)alloc((size_t)N * 64);
    float* x1 = (float*)alloc(featF);
    float* x2 = (float*)alloc(featF);
    float* sums = (float*)alloc((size_t)G * 64 * 4);
    int* cnts = (int*)alloc((size_t)G * 4);

    int2* pk = (int2*)regP;
    float* h = (float*)regP;

    hipMemsetAsync(bhist, 0, MAXK * 4, stream);
    hipMemsetAsync(sums, 0, (size_t)G * 64 * 4, stream);
    hipMemsetAsync(cnts, 0, (size_t)G * 4, stream);

    int cb = (E + CHUNK - 1) / CHUNK;
    bhist_k<<<cb, 512, 0, stream>>>(rows, bhist, E);
    bscan_k<<<1, MAXK, 0, stream>>>(bhist, bstart, bcur, rp, K, E, N);
    binpass_k<<<cb, 512, 0, stream>>>(rows, cols, vals, bcur, pk, E);
    sort_k<<<K, 512, 0, stream>>>(bstart, pk, rp, epk, N);

    int rb = (N + 3) / 4;  // wave-per-row blocks
    dense5_k<<<rb, 256, 0, stream>>>(x, W1, Zq, N);
    spmm_relu_k<<<rb, 256, 0, stream>>>(rp, epk, Zq, b1, x1, N);
    dense64_k<<<rb, 256, 0, stream>>>(x1, W2, Zq, N);
    spmm_relu_k<<<rb, 256, 0, stream>>>(rp, epk, Zq, b2, x2, N);
    dense64_k<<<rb, 256, 0, stream>>>(x2, W3, Zq, N);
    spmm_relu3_k<<<rb, 256, 0, stream>>>(rp, epk, Zq, b3, x1, x2, h, N);

    int pw = (N + 63) / 64;
    pool_k<<<(pw + 3) / 4, 256, 0, stream>>>(h, batch, sums, cnts, N);
    final_k<<<(G + 3) / 4, 256, 0, stream>>>(sums, cnts, Wl, bl, out, G);
}